// Round 7
// baseline (1019.369 us; speedup 1.0000x reference)
//
#include <hip/hip_runtime.h>

// NonLocalMeans: rgb (8,3,1024,1024) f32, search 11x11, patch 5x5, circular.
// out(p) = sum_s w(p,s)*rgb(p-s) / sum_s w(p,s),
// w(p,s) = exp(-sqrt(box5x5((y - y_shift)^2)) * inv_h)
//
// R7 = R6 minus the rgb LDS staging: FIN pixel reads go DIRECTLY to global
// (L1/L2-cached; coalesced; uniform SGPR plane bases + imm -4J offsets).
// Rationale (R6 post-mortem): kernel is LDS-BW-bound (38.4 GB LDS reads
// ~ 556us at 69 TB/s; measured 753us). FIN float4s were 42% of LDS bytes;
// moving them to the idle VMEM/L1/L2 pipe drops LDS to ~25.5 GB AND halves
// LDS size (37 KB -> 16 KB) -> 8 blocks/CU occupancy (TLP hides L1 latency).
// Y and A = K^2*box5x5(y^2) stay in LDS (A must be f32; expand-the-square
// algebra from R2/R3). Interior blocks: zero-VALU addressing (J folds into
// the 13-bit load imm); the 2 x-edge block columns take a &MASK slow path.
// Fences (sched_barrier(0)) keep schedule order = source order = designed
// liveness (R5 lesson); FIN sub-fenced in 3-J groups to cap in-flight loads.
// Same f32 values, same accumulation order as R6 -> bit-identical output.

#define HW (1024 * 1024)
#define W 1024
#define MASK 1023

constexpr int TILE = 32;
constexpr int YREG = 46;    // TILE + 2*7 (shift 5 + patch 2)
constexpr int YPITCH = 48;
constexpr int CREG = 42;    // TILE + 2*5 (A-field tile)
// (1/3 channel mean) * inv_h*log2(e); inv_h = 1/(1+1e-6)
constexpr float K3 = 1.4426935981939074f / 3.0f;

#define SBAR() __builtin_amdgcn_sched_barrier(0)

// 5-tap cross-correlation; c0..c4 in scope at expansion site
#define CR5(W0,W1,W2,W3,W4) \
    fmaf(c4,(W4), fmaf(c3,(W3), fmaf(c2,(W2), fmaf(c1,(W1), c0*(W0)))))

// h_J = 5-tap correlation over ywp[10-J .. 14-J].
// Pass A: J=0..5 (ywp[5..14]); pass B: J=6..10 (ywp[0..8]).
#define ROW_HA(RR)                                                          \
    const float* ycp = &ldsY[yci + (RR) * YPITCH];                          \
    const float* ywp = &ldsY[ywi + (RR) * YPITCH];                          \
    const float c0=ycp[0],c1=ycp[1],c2=ycp[2],c3=ycp[3],c4=ycp[4];          \
    const float w5 =ywp[5], w6 =ywp[6], w7 =ywp[7], w8 =ywp[8], w9 =ywp[9]; \
    const float w10=ywp[10],w11=ywp[11],w12=ywp[12],w13=ywp[13],w14=ywp[14];\
    const float h0 = CR5(w10,w11,w12,w13,w14);                              \
    const float h1 = CR5(w9, w10,w11,w12,w13);                              \
    const float h2 = CR5(w8, w9, w10,w11,w12);                              \
    const float h3 = CR5(w7, w8, w9, w10,w11);                              \
    const float h4 = CR5(w6, w7, w8, w9, w10);                              \
    const float h5 = CR5(w5, w6, w7, w8, w9);

#define ROW_HB(RR)                                                          \
    const float* ycp = &ldsY[yci + (RR) * YPITCH];                          \
    const float* ywp = &ldsY[ywi + (RR) * YPITCH];                          \
    const float c0=ycp[0],c1=ycp[1],c2=ycp[2],c3=ycp[3],c4=ycp[4];          \
    const float w0 =ywp[0], w1 =ywp[1], w2 =ywp[2], w3 =ywp[3], w4 =ywp[4]; \
    const float w5 =ywp[5], w6 =ywp[6], w7 =ywp[7], w8 =ywp[8];             \
    const float h6  = CR5(w4, w5, w6, w7, w8);                              \
    const float h7  = CR5(w3, w4, w5, w6, w7);                              \
    const float h8  = CR5(w2, w3, w4, w5, w6);                              \
    const float h9  = CR5(w1, w2, w3, w4, w5);                              \
    const float h10 = CR5(w0, w1, w2, w3, w4);

// per-pass vertical partials, named scalars, block-scoped
#define VDECLA(VD) float VD##_0, VD##_1, VD##_2, VD##_3, VD##_4, VD##_5
#define VSETA(VD)  VD##_0 =h0; VD##_1 =h1; VD##_2 =h2;                      \
                   VD##_3 =h3; VD##_4 =h4; VD##_5 =h5
#define VADDA(VD)  VD##_0+=h0; VD##_1+=h1; VD##_2+=h2;                      \
                   VD##_3+=h3; VD##_4+=h4; VD##_5+=h5
#define VDECLB(VD) float VD##_6, VD##_7, VD##_8, VD##_9, VD##_10
#define VSETB(VD)  VD##_6 =h6; VD##_7 =h7; VD##_8 =h8;                      \
                   VD##_9 =h9; VD##_10=h10
#define VADDB(VD)  VD##_6+=h6; VD##_7+=h7; VD##_8+=h8;                      \
                   VD##_9+=h9; VD##_10+=h10

// finalize one (YO,J): px from GLOBAL (planes gr/gg/gb, index IDXE),
// A(p-s) from LDS; S = Ac + Aw - 2*cross; dist = sqrt(|S|); w = exp2(-dist).
#define FIN1G(YO, VD, J, IDXE) do {                                         \
    const int gi = (IDXE);                                                  \
    const float pr = gr[gi];                                                \
    const float pg = gg[gi];                                                \
    const float pb = gb[gi];                                                \
    const float aw = ldsA[ari - (J)];                                       \
    float s = fmaf(-2.0f, VD##_##J, acb + aw);                              \
    float dist = __builtin_amdgcn_sqrtf(__builtin_fabsf(s));                \
    float wgt  = __builtin_amdgcn_exp2f(-dist);                             \
    aR##YO = fmaf(wgt, pr, aR##YO);                                         \
    aG##YO = fmaf(wgt, pg, aG##YO);                                         \
    aB##YO = fmaf(wgt, pb, aB##YO);                                         \
    aW##YO += wgt;                                                          \
} while (0)

#define FIN_HEADG(YO)                                                       \
    const int rowo = ((by0 + y0 + (YO) - dy) & MASK) << 10;                 \
    const int ari  = cri + (YO) * CREG;                                     \
    const float acb = ldsA[abi + (YO) * CREG];

// fast path (interior in x): gi = rowo + txo - J; J folds into load imm
#define FIN_AF(YO, VD) do { FIN_HEADG(YO)                                   \
    const int pre = rowo + txo;                                             \
    FIN1G(YO,VD,0,pre  ); FIN1G(YO,VD,1,pre-1); FIN1G(YO,VD,2,pre-2);       \
    SBAR();                                                                 \
    FIN1G(YO,VD,3,pre-3); FIN1G(YO,VD,4,pre-4); FIN1G(YO,VD,5,pre-5);       \
} while (0)

#define FIN_BF(YO, VD) do { FIN_HEADG(YO)                                   \
    const int pre = rowo + txo;                                             \
    FIN1G(YO,VD,6,pre-6); FIN1G(YO,VD,7,pre-7); FIN1G(YO,VD,8,pre-8);       \
    SBAR();                                                                 \
    FIN1G(YO,VD,9,pre-9); FIN1G(YO,VD,10,pre-10);                           \
} while (0)

// edge path (x wraps): per-J & MASK
#define FIN_AE(YO, VD) do { FIN_HEADG(YO)                                   \
    FIN1G(YO,VD,0,rowo+((txo  )&MASK)); FIN1G(YO,VD,1,rowo+((txo-1)&MASK)); \
    FIN1G(YO,VD,2,rowo+((txo-2)&MASK));                                     \
    SBAR();                                                                 \
    FIN1G(YO,VD,3,rowo+((txo-3)&MASK)); FIN1G(YO,VD,4,rowo+((txo-4)&MASK)); \
    FIN1G(YO,VD,5,rowo+((txo-5)&MASK));                                     \
} while (0)

#define FIN_BE(YO, VD) do { FIN_HEADG(YO)                                   \
    FIN1G(YO,VD,6,rowo+((txo-6)&MASK)); FIN1G(YO,VD,7,rowo+((txo-7)&MASK)); \
    FIN1G(YO,VD,8,rowo+((txo-8)&MASK));                                     \
    SBAR();                                                                 \
    FIN1G(YO,VD,9,rowo+((txo-9)&MASK)); FIN1G(YO,VD,10,rowo+((txo-10)&MASK));\
} while (0)

#define STORE(YO) do {                                                      \
    const int off = (by0 + y0 + (YO)) * W + bx0 + tx;                       \
    const float inv = 1.0f / aW##YO;                                        \
    obase[off]          = aR##YO * inv;                                     \
    obase[off + HW]     = aG##YO * inv;                                     \
    obase[off + 2 * HW] = aB##YO * inv;                                     \
} while (0)

// squared 5-tap row sum for the A-field precompute (y pre-scaled by K)
#define A5(p) fmaf((p)[4],(p)[4], fmaf((p)[3],(p)[3], fmaf((p)[2],(p)[2],   \
              fmaf((p)[1],(p)[1], (p)[0]*(p)[0]))))

// the dy loop, parameterized by FIN macro pair (fast / edge)
#define DY_BODY(FINAM, FINBM)                                               \
    _Pragma("clang loop unroll(disable)")                                   \
    for (int dy = -5; dy <= 5; ++dy) {                                      \
        const int ywi = (y0 + 5 - dy) * YPITCH + tx;                        \
        const int cri = (y0 - dy + 5) * CREG + tx + 10;                     \
        {   /* pass A: J = 0..5 (dx = -5..0) */                             \
            VDECLA(v0); VDECLA(v1); VDECLA(v2); VDECLA(v3);                 \
            { ROW_HA(0); VSETA(v0); }                          SBAR();      \
            { ROW_HA(1); VADDA(v0); VSETA(v1); }               SBAR();      \
            { ROW_HA(2); VADDA(v0); VADDA(v1); VSETA(v2); }    SBAR();      \
            { ROW_HA(3); VADDA(v0); VADDA(v1); VADDA(v2); VSETA(v3); } SBAR(); \
            { ROW_HA(4); VADDA(v0); VADDA(v1); VADDA(v2); VADDA(v3); } SBAR(); \
            FINAM(0, v0);                                      SBAR();      \
            { ROW_HA(5); VADDA(v1); VADDA(v2); VADDA(v3); }    SBAR();      \
            FINAM(1, v1);                                      SBAR();      \
            { ROW_HA(6); VADDA(v2); VADDA(v3); }               SBAR();      \
            FINAM(2, v2);                                      SBAR();      \
            { ROW_HA(7); VADDA(v3); }                          SBAR();      \
            FINAM(3, v3);                                      SBAR();      \
        }                                                                   \
        {   /* pass B: J = 6..10 (dx = 1..5) */                             \
            VDECLB(v0); VDECLB(v1); VDECLB(v2); VDECLB(v3);                 \
            { ROW_HB(0); VSETB(v0); }                          SBAR();      \
            { ROW_HB(1); VADDB(v0); VSETB(v1); }               SBAR();      \
            { ROW_HB(2); VADDB(v0); VADDB(v1); VSETB(v2); }    SBAR();      \
            { ROW_HB(3); VADDB(v0); VADDB(v1); VADDB(v2); VSETB(v3); } SBAR(); \
            { ROW_HB(4); VADDB(v0); VADDB(v1); VADDB(v2); VADDB(v3); } SBAR(); \
            FINBM(0, v0);                                      SBAR();      \
            { ROW_HB(5); VADDB(v1); VADDB(v2); VADDB(v3); }    SBAR();      \
            FINBM(1, v1);                                      SBAR();      \
            { ROW_HB(6); VADDB(v2); VADDB(v3); }               SBAR();      \
            FINBM(2, v2);                                      SBAR();      \
            { ROW_HB(7); VADDB(v3); }                          SBAR();      \
            FINBM(3, v3);                                      SBAR();      \
        }                                                                   \
    }

__global__ void __launch_bounds__(256)
nlm_fused(const float* __restrict__ rgb, float* __restrict__ out) {
    __shared__ float ldsY[YREG * YPITCH];   // 8832 B (K-scaled luminance)
    __shared__ float ldsA[CREG * CREG];     // 7056 B (K^2 * box5x5(y^2))
                                            // total 15888 B -> 8 blocks/CU

    const int tid = threadIdx.x;
    const int batch = blockIdx.z;
    const int by0 = blockIdx.y * TILE;
    const int bx0 = blockIdx.x * TILE;

    const float* gr = rgb + (size_t)batch * 3 * HW;   // plane bases (uniform)
    const float* gg = gr + HW;
    const float* gb = gr + 2 * HW;

    // ---- stage K-scaled luminance tile (mean over channels), halo 7 ----
    for (int i = tid; i < YREG * YREG; i += 256) {
        int ry = i / YREG, rx = i - ry * YREG;
        int gy = (by0 + ry - 7) & MASK;
        int gx = (bx0 + rx - 7) & MASK;
        int off = gy * W + gx;
        float v = (gr[off] + gg[off] + gb[off]) * K3;
        ldsY[ry * YPITCH + rx] = v;
    }
    __syncthreads();    // Y complete before A-field compute

    // ---- A = K^2 * box5x5(y^2) over the 42x42 (halo 5) region ----
    for (int i = tid; i < CREG * CREG; i += 256) {
        int ry = i / CREG, rx = i - ry * CREG;
        const float* yb = &ldsY[ry * YPITCH + rx];   // A window = Y rows ry..ry+4
        float a =  A5(yb);
        a += A5(yb + YPITCH);
        a += A5(yb + 2 * YPITCH);
        a += A5(yb + 3 * YPITCH);
        a += A5(yb + 4 * YPITCH);
        ldsA[i] = a;
    }
    __syncthreads();

    const int tx = tid & 31;          // output column within tile
    const int y0 = (tid >> 5) * 4;    // 4-pixel column run per thread

    // loop-invariant scalar indices
    const int yci = (y0 + 5) * YPITCH + tx + 5;   // center rows, +RR*YPITCH
    const int abi = (y0 + 5) * CREG + tx + 5;     // A(center),  +YO*CREG
    const int txo = bx0 + tx + 5;                 // global col base, -J

    float aR0=0.f, aG0=0.f, aB0=0.f, aW0=0.f;
    float aR1=0.f, aG1=0.f, aB1=0.f, aW1=0.f;
    float aR2=0.f, aG2=0.f, aB2=0.f, aW2=0.f;
    float aR3=0.f, aG3=0.f, aB3=0.f, aW3=0.f;

    // x-interior blocks: txo-J in [bx0-5, bx0+36] never wraps for bx0 in [32,960]
    if (bx0 >= 32 && bx0 <= 1024 - 64) {
        DY_BODY(FIN_AF, FIN_BF);
    } else {
        DY_BODY(FIN_AE, FIN_BE);
    }

    float* obase = out + (size_t)batch * 3 * HW;
    STORE(0);
    STORE(1);
    STORE(2);
    STORE(3);
}

extern "C" void kernel_launch(void* const* d_in, const int* in_sizes, int n_in,
                              void* d_out, int out_size, void* d_ws, size_t ws_size,
                              hipStream_t stream) {
    const float* rgb = (const float*)d_in[0];
    float* out = (float*)d_out;
    dim3 grid(W / TILE, W / TILE, 8);
    dim3 block(256, 1, 1);
    hipLaunchKernelGGL(nlm_fused, grid, block, 0, stream, rgb, out);
}